// Round 5
// baseline (232.587 us; speedup 1.0000x reference)
//
#include <hip/hip_runtime.h>
#include <math.h>

// Problem constants (fixed by reference)
#define N_TOT 16384
#define DIM   256
#define KCB   4096

typedef __attribute__((ext_vector_type(8)))  short s8v;   // 8 bf16 = 4 VGPR
typedef __attribute__((ext_vector_type(16))) float f16v;  // MFMA 32x32 accumulator

// ---------------- ws layout (bytes) ----------------
// [0)      cbn    : 4096 f32 (||e_k||^2)
// [16384)  counts : 4096 f32
// [32768)  loss   : 1 f32 (+pad)
// [32832)  pk     : 16384 u64 (packed argmin merge)   -> 163904
// [163904) cbF    : fragment-linear split codebook, 128 tiles x 32KB = 4MB
//          tile t = cols [32t,32t+32): h 16KB then l 16KB.
//          h ushort idx within tile: ks*512 + khalf*256 + col*8 + j
//          (k = ks*16 + khalf*8 + j)  == LDS order  base + ks*1024 + lane*16
//          with lane = col + 32*khalf  -> global_load_lds is a linear memcpy.
#define PK_OFF   32832
#define CBF_OFF  163904
#define WS_NEED  4358208ull
#define ZERO_W   36880   // f32 words from ws[4096] covering counts+loss+pk

__device__ __forceinline__ void gload16(const void* g, void* l) {
  __builtin_amdgcn_global_load_lds(
      (const __attribute__((address_space(1))) unsigned int*)g,
      (__attribute__((address_space(3))) unsigned int*)l, 16, 0, 0);
}

// ---- codebook prep: zero ws counters, norms, fragment-linear h/l split ----
// 128 blocks (one per 32-col tile) x 256 threads. t -> (col = t>>3, j = t&7).
__global__ __launch_bounds__(256)
void cb_prep_k(const float* __restrict__ cb, float* __restrict__ ws) {
  const int t = threadIdx.x, tile = blockIdx.x;
  // fused zeroing of counts + loss + pk
  for (int i = tile * 256 + t; i < ZERO_W; i += 128 * 256) ws[KCB + i] = 0.0f;

  const int col = t >> 3, j = t & 7;
  const int c0  = tile * 32;
  ushort* tb = (ushort*)((char*)ws + CBF_OFF) + (size_t)tile * 16384;
  const float* src = cb + (size_t)(c0 + col) * DIM;
  float s = 0.0f;
  #pragma unroll
  for (int ks = 0; ks < 16; ++ks) {
    #pragma unroll
    for (int kh = 0; kh < 2; ++kh) {
      float x = src[ks * 16 + kh * 8 + j];
      s += x * x;
      unsigned xb = __float_as_uint(x);
      unsigned hb = xb & 0xFFFF0000u;
      float lf = x - __uint_as_float(hb);   // exact
      tb[ks * 512 + kh * 256 + t]        = (ushort)(xb >> 16);
      tb[8192 + ks * 512 + kh * 256 + t] = (ushort)(__float_as_uint(lf) >> 16);
    }
  }
  s += __shfl_down(s, 4, 8);
  s += __shfl_down(s, 2, 8);
  s += __shfl_down(s, 1, 8);
  if (j == 0) ws[c0 + col] = s;
}

// ---------------- main MFMA kernel ----------------
// 256 blocks x 256 threads (4 waves), 1 block/CU, 1 wave/SIMD (intentional).
// Block = 256 rows x 1024 cols (mb = blockIdx>>2, cq = blockIdx&3).
// ROUND-5 THEORY: at 32 rows/wave the LDS port (85 B/clk measured) is loaded
// exactly 1:1 with the MFMA pipe (3084 vs 3072 clk/tile/CU) -> MfmaUtil can
// never exceed ~50% (rounds 0/2/4 all ~41% across three schedules).
// 64 rows/wave halves LDS bytes per FLOP: each (bh,bl) pair feeds 6 MFMAs.
// Round 3 proved correctness + reg-fit (VGPR 224 + AGPR, no spill) but ran
// 134us due to: A-stage bank conflicts, per-tile vmcnt(0) drains at 1
// wave/SIMD, shallow B-frag prefetch. This version fixes all three:
//  - conflict-free A-stage (round-0 t>>3 pattern),
//  - counted vmcnt(8) + tri-buffered B (tile tt+1 stays in flight across
//    the barrier; never drain to 0 until the last tile),
//  - explicit ks+1 register ping-pong of (bh,bl) so the single wave always
//    has the next fragments loading under 6 in-flight MFMA chains,
//  - -0.5||e||^2 folded into the h-accumulator init (epilogue trim).
#define AP 260   // A-stage pitch (floats): 4-float pad -> 16B-aligned, 2-way-only banks

__global__ __launch_bounds__(256, 1)
void vq_mfma_k(const float* __restrict__ ze, float* __restrict__ ws) {
  __shared__ __align__(16) char ldsU[3 * 32768 + 4096];  // B x3 + sCbn(4KB); A-stage reuses [0,33280)
  float* sCbn = (float*)(ldsU + 3 * 32768);

  const int t    = threadIdx.x;
  const int lane = t & 63;
  const int w    = t >> 6;          // 0..3
  const int ln31 = lane & 31;
  const int hl   = lane >> 5;
  const int mb   = blockIdx.x >> 2;
  const int cq   = blockIdx.x & 3;
  const int m0   = mb * 256;

  const float* cbn = ws;
  unsigned long long* pk = (unsigned long long*)((char*)ws + PK_OFF);
  const char* cbF = (const char*)ws + CBF_OFF;

  // ---- A into registers: 8 chunks of 32 rows staged fp32 through LDS.
  // Wave w owns rows m0 + w*64 .. +63 (chunks 2w, 2w+1 -> rb 0,1).
  // Stage pattern = round-0's conflict-free one (r = t>>3, f0 = t&7).
  s8v ah[2][16], al[2][16];
  float* Af = (float*)ldsU;
  for (int c = 0; c < 8; ++c) {
    __syncthreads();
    {
      int r  = t >> 3;          // 0..31
      int f0 = t & 7;
      const float* src = ze + (size_t)(m0 + c * 32 + r) * DIM;
      #pragma unroll
      for (int i = 0; i < 8; ++i) {
        int f = f0 + 8 * i;
        *(float4*)&Af[r * AP + f * 4] = *(const float4*)(src + f * 4);
      }
    }
    __syncthreads();
    if (w == (c >> 1)) {
      const int rb = c & 1;
      const int rl = ln31;
      #pragma unroll
      for (int ks = 0; ks < 16; ++ks) {
        float4 q0 = *(const float4*)&Af[rl * AP + ks * 16 + hl * 8];
        float4 q1 = *(const float4*)&Af[rl * AP + ks * 16 + hl * 8 + 4];
        float xs[8] = {q0.x, q0.y, q0.z, q0.w, q1.x, q1.y, q1.z, q1.w};
        #pragma unroll
        for (int j = 0; j < 8; ++j) {
          unsigned xb = __float_as_uint(xs[j]);
          unsigned hb = xb & 0xFFFF0000u;
          float lf = xs[j] - __uint_as_float(hb);
          ah[rb][ks][j] = (short)(xb >> 16);
          al[rb][ks][j] = (short)(__float_as_uint(lf) >> 16);
        }
      }
    }
  }
  // stage cbn for this block's 1024 cols (region disjoint from A-stage)
  #pragma unroll
  for (int i = 0; i < 4; ++i) sCbn[t + 256 * i] = cbn[cq * 1024 + t + 256 * i];
  __syncthreads();   // A-region reads + cbn writes done before B staging overwrites ldsU

  const char* qbase = cbF + (size_t)cq * 32 * 32768;   // 32 tiles of 32 cols

  // prologue: issue tiles 0,1 (8 x 1KB per wave each = 32KB/tile)
  #pragma unroll
  for (int pt = 0; pt < 2; ++pt) {
    const char* g = qbase + (size_t)pt * 32768 + (size_t)w * 8192 + (size_t)lane * 16;
    char* lp = ldsU + pt * 32768 + w * 8192;
    #pragma unroll
    for (int ii = 0; ii < 8; ++ii) gload16(g + ii * 1024, lp + ii * 1024);
  }

  float best[32];
  int   bidx[32];
  #pragma unroll
  for (int r = 0; r < 32; ++r) { best[r] = -1e30f; bidx[r] = 0; }

  const char* bR = ldsU;                 // read buf for tile tt
  char*       bW = ldsU + 2 * 32768;     // write buf for tile tt+2

  #pragma unroll 1
  for (int tt = 0; tt < 32; ++tt) {
    // counted wait: tile tt landed; tile tt+1's 8 loads stay in flight.
    if (tt == 31) { asm volatile("s_waitcnt vmcnt(0)" ::: "memory"); }
    else          { asm volatile("s_waitcnt vmcnt(8)" ::: "memory"); }
    __builtin_amdgcn_s_barrier();
    __builtin_amdgcn_sched_barrier(0);   // nothing hoists above the barrier

    if (tt + 2 < 32) {
      const char* g = qbase + (size_t)(tt + 2) * 32768 + (size_t)w * 8192 + (size_t)lane * 16;
      char* lp = bW + w * 8192;
      #pragma unroll
      for (int ii = 0; ii < 8; ++ii) gload16(g + ii * 1024, lp + ii * 1024);
    }

    const int   c0      = cq * 1024 + tt * 32;
    const float half_cv = 0.5f * sCbn[tt * 32 + ln31];
    const s8v*  bp      = (const s8v*)(bR + (size_t)lane * 16);  // ks stride 64 s8v; l-half at +1024

    f16v h0, x0, h1, x1;
    #pragma unroll
    for (int r = 0; r < 16; ++r) {
      h0[r] = -half_cv; h1[r] = -half_cv; x0[r] = 0.0f; x1[r] = 0.0f;
    }

    // explicit ks+1 register ping-pong: next (bh,bl) loads run under 6 MFMAs
    s8v cbh = bp[0], cbl = bp[1024];
    __builtin_amdgcn_s_setprio(1);
    #pragma unroll
    for (int ks = 0; ks < 16; ++ks) {
      s8v nbh = cbh, nbl = cbl;
      if (ks < 15) { nbh = bp[(ks + 1) * 64]; nbl = bp[1024 + (ks + 1) * 64]; }
      h0 = __builtin_amdgcn_mfma_f32_32x32x16_bf16(ah[0][ks], cbh, h0, 0, 0, 0);
      h1 = __builtin_amdgcn_mfma_f32_32x32x16_bf16(ah[1][ks], cbh, h1, 0, 0, 0);
      x0 = __builtin_amdgcn_mfma_f32_32x32x16_bf16(ah[0][ks], cbl, x0, 0, 0, 0);
      x1 = __builtin_amdgcn_mfma_f32_32x32x16_bf16(ah[1][ks], cbl, x1, 0, 0, 0);
      x0 = __builtin_amdgcn_mfma_f32_32x32x16_bf16(al[0][ks], cbh, x0, 0, 0, 0);
      x1 = __builtin_amdgcn_mfma_f32_32x32x16_bf16(al[1][ks], cbh, x1, 0, 0, 0);
      cbh = nbh; cbl = nbl;
    }
    __builtin_amdgcn_s_setprio(0);

    // score = dot - 0.5||e||^2 (norm folded into h init);
    // cols ascend with tt => '>' keeps first min
    #pragma unroll
    for (int r = 0; r < 16; ++r) {
      float s0 = h0[r] + x0[r];
      if (s0 > best[r])      { best[r]      = s0; bidx[r]      = c0 + ln31; }
      float s1 = h1[r] + x1[r];
      if (s1 > best[16 + r]) { best[16 + r] = s1; bidx[16 + r] = c0 + ln31; }
    }

    bR += 32768; if (bR == ldsU + 3 * 32768) bR = ldsU;
    bW += 32768; if (bW == ldsU + 3 * 32768) bW = ldsU;
  }

  // ---- cross-lane argmax over the 32 cols (masks<32 keep hl halves separate),
  // then device-scope packed atomicMax merge across the 4 col-split blocks ----
  #pragma unroll
  for (int r = 0; r < 32; ++r) {
    float s = best[r];
    int   c = bidx[r];
    #pragma unroll
    for (int mk = 1; mk < 32; mk <<= 1) {
      float os = __shfl_xor(s, mk, 64);
      int   oc = __shfl_xor(c, mk, 64);
      if (os > s || (os == s && oc < c)) { s = os; c = oc; }
    }
    if (ln31 == 0) {
      int rb = r >> 4, rr = r & 15;
      int row = m0 + w * 64 + rb * 32 + (rr & 3) + 8 * (rr >> 2) + 4 * hl;
      unsigned u = __float_as_uint(s);
      unsigned enc = (u & 0x80000000u) ? ~u : (u | 0x80000000u);
      unsigned long long p = ((unsigned long long)enc << 32) | (unsigned)(KCB - 1 - c);
      atomicMax(&pk[row], p);
    }
  }
}

// ---- gather: indices out, counts, zq, loss partials ----
__global__ __launch_bounds__(256)
void gather_k(const float* __restrict__ ze, const float* __restrict__ cb,
              float* __restrict__ ws, float* __restrict__ out) {
  __shared__ int sIdx[64];
  const int t  = threadIdx.x;
  const int m0 = blockIdx.x * 64;
  float* counts   = ws + KCB;
  float* loss_sum = ws + 2 * KCB;
  const unsigned long long* pk = (const unsigned long long*)((const char*)ws + PK_OFF);

  if (t < 64) {
    unsigned long long p = pk[m0 + t];
    int col = KCB - 1 - (int)(unsigned)(p & 0xFFFFFFFFull);
    out[m0 + t] = (float)col;
    sIdx[t] = col;
    atomicAdd(&counts[col], 1.0f);
  }
  __syncthreads();

  float* out_zq = out + N_TOT;
  const int w = t >> 6, ln = t & 63;
  float lsum = 0.0f;
  #pragma unroll
  for (int p = 0; p < 16; ++p) {
    int r = w + 4 * p;
    float4 cvv = *(const float4*)(cb + (size_t)sIdx[r] * DIM + ln * 4);
    float4 zv  = *(const float4*)(ze + (size_t)(m0 + r) * DIM + ln * 4);
    *(float4*)(out_zq + (size_t)(m0 + r) * DIM + ln * 4) = cvv;
    float dx = cvv.x - zv.x, dy = cvv.y - zv.y, dz = cvv.z - zv.z, dw = cvv.w - zv.w;
    lsum += dx * dx + dy * dy + dz * dz + dw * dw;
  }
  #pragma unroll
  for (int off = 32; off > 0; off >>= 1) lsum += __shfl_down(lsum, off, 64);
  if (ln == 0) atomicAdd(loss_sum, lsum);
}

// ---------------- fallback (round-1 fp32 path, if ws too small) ----------------
__global__ void zero_ws_k(float* __restrict__ ws, int nw) {
  int i = blockIdx.x * 256 + threadIdx.x;
  if (i < nw) ws[KCB + i] = 0.0f;
}

__global__ void cbnorm_k(const float* __restrict__ cb, float* __restrict__ ws) {
  int row  = blockIdx.x * 4 + (threadIdx.x >> 6);
  int lane = threadIdx.x & 63;
  float4 v = *(const float4*)(cb + (size_t)row * DIM + lane * 4);
  float s = v.x*v.x + v.y*v.y + v.z*v.z + v.w*v.w;
  #pragma unroll
  for (int off = 32; off > 0; off >>= 1) s += __shfl_down(s, off, 64);
  if (lane == 0) ws[row] = s;
}

#define FBM 32
#define FBN 64
#define FBD 128
__global__ __launch_bounds__(256, 4)
void vq_main_k(const float* __restrict__ ze, const float* __restrict__ cb,
               float* __restrict__ ws, float* __restrict__ out) {
  __shared__ float As[FBM * FBD];
  __shared__ float Bs[FBN * FBD];
  __shared__ float red_d[FBM * 16];
  __shared__ int   red_i[FBM * 16];
  __shared__ int   sIdx[FBM];

  const int t  = threadIdx.x;
  const int tx = t & 15;
  const int ty = t >> 4;
  const int m0 = blockIdx.x * FBM;

  const float* cbn = ws;
  float* counts    = ws + KCB;
  float* loss_sum  = ws + 2 * KCB;

  float best0 = 1e30f, best1 = 1e30f;
  int   bidx0 = 0,     bidx1 = 0;
  const int sA = ty & 7;
  const int sB = tx & 7;

  for (int kt = 0; kt < KCB / FBN; ++kt) {
    float cbnj[4];
    #pragma unroll
    for (int j = 0; j < 4; ++j) cbnj[j] = cbn[kt * FBN + tx + 16 * j];
    float acc[2][4];
    #pragma unroll
    for (int i = 0; i < 2; ++i)
      #pragma unroll
      for (int j = 0; j < 4; ++j) acc[i][j] = 0.0f;

    for (int dc = 0; dc < DIM / FBD; ++dc) {
      __syncthreads();
      {
        int c  = t & 31;
        int rb = t >> 5;
        #pragma unroll
        for (int p = 0; p < 4; ++p) {
          int r = rb + 8 * p;
          float4 v = *(const float4*)(ze + (size_t)(m0 + r) * DIM + dc * FBD + c * 4);
          *(float4*)&As[r * FBD + ((c ^ (r & 7)) << 2)] = v;
        }
        #pragma unroll
        for (int p = 0; p < 8; ++p) {
          int r = rb + 8 * p;
          float4 v = *(const float4*)(cb + (size_t)(kt * FBN + r) * DIM + dc * FBD + c * 4);
          *(float4*)&Bs[r * FBD + ((c ^ (r & 7)) << 2)] = v;
        }
      }
      __syncthreads();
      #pragma unroll 8
      for (int ds = 0; ds < FBD / 4; ++ds) {
        float4 a0 = *(const float4*)&As[ty * FBD + ((ds ^ sA) << 2)];
        float4 a1 = *(const float4*)&As[(ty + 16) * FBD + ((ds ^ sA) << 2)];
        float4 b[4];
        #pragma unroll
        for (int j = 0; j < 4; ++j)
          b[j] = *(const float4*)&Bs[(tx + 16 * j) * FBD + ((ds ^ sB) << 2)];
        #pragma unroll
        for (int j = 0; j < 4; ++j) {
          acc[0][j] = fmaf(a0.x, b[j].x, acc[0][j]);
          acc[0][j] = fmaf(a0.y, b[j].y, acc[0][j]);
          acc[0][j] = fmaf(a0.z, b[j].z, acc[0][j]);
          acc[0][j] = fmaf(a0.w, b[j].w, acc[0][j]);
          acc[1][j] = fmaf(a1.x, b[j].x, acc[1][j]);
          acc[1][j] = fmaf(a1.y, b[j].y, acc[1][j]);
          acc[1][j] = fmaf(a1.z, b[j].z, acc[1][j]);
          acc[1][j] = fmaf(a1.w, b[j].w, acc[1][j]);
        }
      }
    }
    #pragma unroll
    for (int j = 0; j < 4; ++j) {
      int kg = kt * FBN + tx + 16 * j;
      float d0 = cbnj[j] - 2.0f * acc[0][j];
      float d1 = cbnj[j] - 2.0f * acc[1][j];
      if (d0 < best0) { best0 = d0; bidx0 = kg; }
      if (d1 < best1) { best1 = d1; bidx1 = kg; }
    }
  }

  __syncthreads();
  red_d[ty * 16 + tx] = best0;        red_i[ty * 16 + tx] = bidx0;
  red_d[(ty + 16) * 16 + tx] = best1; red_i[(ty + 16) * 16 + tx] = bidx1;
  __syncthreads();

  if (t < FBM) {
    float bd = red_d[t * 16]; int bi = red_i[t * 16];
    #pragma unroll
    for (int q = 1; q < 16; ++q) {
      float d = red_d[t * 16 + q]; int i2 = red_i[t * 16 + q];
      if (d < bd || (d == bd && i2 < bi)) { bd = d; bi = i2; }
    }
    out[m0 + t] = (float)bi;
    sIdx[t] = bi;
    atomicAdd(&counts[bi], 1.0f);
  }
  __syncthreads();

  float* out_zq = out + N_TOT;
  const int wv = t >> 6, ln = t & 63;
  float lsum = 0.0f;
  #pragma unroll
  for (int p = 0; p < 8; ++p) {
    int r = wv + 4 * p;
    float4 cvv = *(const float4*)(cb + (size_t)sIdx[r] * DIM + ln * 4);
    float4 zv  = *(const float4*)(ze + (size_t)(m0 + r) * DIM + ln * 4);
    *(float4*)(out_zq + (size_t)(m0 + r) * DIM + ln * 4) = cvv;
    float dx = cvv.x - zv.x, dy = cvv.y - zv.y, dz = cvv.z - zv.z, dw = cvv.w - zv.w;
    lsum += dx*dx + dy*dy + dz*dz + dw*dw;
  }
  #pragma unroll
  for (int off = 32; off > 0; off >>= 1) lsum += __shfl_down(lsum, off, 64);
  if (ln == 0) atomicAdd(loss_sum, lsum);
}

__global__ void finalize_k(const float* __restrict__ ws, float* __restrict__ out) {
  __shared__ float red[256];
  int t = threadIdx.x;
  const float* counts = ws + KCB;
  float s = 0.0f;
  for (int k = t; k < KCB; k += 256) {
    float p = counts[k] * 0.1f;
    s += p * logf(p + 1e-10f);
  }
  red[t] = s;
  __syncthreads();
  for (int q = 128; q > 0; q >>= 1) { if (t < q) red[t] += red[t + q]; __syncthreads(); }
  if (t == 0) {
    float loss = ws[2 * KCB] / (float)((size_t)N_TOT * DIM);
    float* o = out + N_TOT + (size_t)N_TOT * DIM;
    o[0] = loss;
    o[1] = loss;
    o[2] = expf(-red[0]);
  }
}

extern "C" void kernel_launch(void* const* d_in, const int* in_sizes, int n_in,
                              void* d_out, int out_size, void* d_ws, size_t ws_size,
                              hipStream_t stream) {
  const float* ze = (const float*)d_in[0];
  const float* cb = (const float*)d_in[1];
  float* out = (float*)d_out;
  float* ws  = (float*)d_ws;

  if (ws_size >= WS_NEED) {
    cb_prep_k<<<128, 256, 0, stream>>>(cb, ws);
    vq_mfma_k<<<256, 256, 0, stream>>>(ze, ws);
    gather_k<<<N_TOT / 64, 256, 0, stream>>>(ze, cb, ws, out);
  } else {
    zero_ws_k<<<(KCB + 1 + 255) / 256, 256, 0, stream>>>(ws, KCB + 1);
    cbnorm_k<<<KCB / 4, 256, 0, stream>>>(cb, ws);
    vq_main_k<<<N_TOT / FBM, 256, 0, stream>>>(ze, cb, ws, out);
  }
  finalize_k<<<1, 256, 0, stream>>>(ws, out);
}

// Round 6
// 215.332 us; speedup vs baseline: 1.0801x; 1.0801x over previous
//
#include <hip/hip_runtime.h>
#include <math.h>

// Problem constants (fixed by reference)
#define N_TOT 16384
#define DIM   256
#define KCB   4096

typedef __attribute__((ext_vector_type(8)))  short s8v;   // 8 bf16 = 4 VGPR
typedef __attribute__((ext_vector_type(16))) float f16v;  // MFMA 32x32 accumulator

// ---------------- ws layout (bytes) ----------------
// [0)      cbn    : 4096 f32 (||e_k||^2)
// [16384)  counts : 4096 f32
// [32768)  loss   : 1 f32 (+pad)
// [32832)  pk     : 16384 u64 (packed argmin merge)   -> 163904
// [163904) cbF    : fragment-linear split codebook, 128 tiles x 32KB = 4MB
//          tile t = cols [32t,32t+32): h 16KB then l 16KB.
//          h ushort idx within tile: ks*512 + khalf*256 + col*8 + j
//          (k = ks*16 + khalf*8 + j)  == fragment order base + ks*1024 + lane*16
//          with lane = col + 32*khalf  -> per-wave loads are linear 1KB bursts.
#define PK_OFF   32832
#define CBF_OFF  163904
#define WS_NEED  4358208ull
#define ZERO_W   36880   // f32 words from ws[4096] covering counts+loss+pk

// ---- codebook prep: zero ws counters, norms, fragment-linear h/l split ----
// 128 blocks (one per 32-col tile) x 256 threads. t -> (col = t>>3, j = t&7).
__global__ __launch_bounds__(256)
void cb_prep_k(const float* __restrict__ cb, float* __restrict__ ws) {
  const int t = threadIdx.x, tile = blockIdx.x;
  // fused zeroing of counts + loss + pk
  for (int i = tile * 256 + t; i < ZERO_W; i += 128 * 256) ws[KCB + i] = 0.0f;

  const int col = t >> 3, j = t & 7;
  const int c0  = tile * 32;
  ushort* tb = (ushort*)((char*)ws + CBF_OFF) + (size_t)tile * 16384;
  const float* src = cb + (size_t)(c0 + col) * DIM;
  float s = 0.0f;
  #pragma unroll
  for (int ks = 0; ks < 16; ++ks) {
    #pragma unroll
    for (int kh = 0; kh < 2; ++kh) {
      float x = src[ks * 16 + kh * 8 + j];
      s += x * x;
      unsigned xb = __float_as_uint(x);
      unsigned hb = xb & 0xFFFF0000u;
      float lf = x - __uint_as_float(hb);   // exact
      tb[ks * 512 + kh * 256 + t]        = (ushort)(xb >> 16);
      tb[8192 + ks * 512 + kh * 256 + t] = (ushort)(__float_as_uint(lf) >> 16);
    }
  }
  s += __shfl_down(s, 4, 8);
  s += __shfl_down(s, 2, 8);
  s += __shfl_down(s, 1, 8);
  if (j == 0) ws[c0 + col] = s;
}

// ---------------- main MFMA kernel ----------------
// 256 blocks x 512 threads (8 waves), 1 block/CU. Block = 256 rows x 1024
// cols (mb = blockIdx>>2, cq = blockIdx&3), 32 rows/wave.
// ROUND-6 THEORY: rounds 0/2/4 proved the three pipes (MFMA 40% + LDS-port
// 40% + VALU 18%) run fully SERIALIZED under every LDS-staged schedule --
// B through the CU-shared LDS port with 8x per-wave re-read pins LDS demand
// 1:1 with MFMA demand. This version deletes the LDS path for B entirely:
// fragments are loaded global->VGPR (cbF is L2-resident; all 8 waves read
// identical addresses per ks, so 7/8 of reads hit the 32KB L1 -- the
// redundancy moves to an idle pipe). No __syncthreads / vmcnt drains in the
// main loop; a bare s_barrier per tile keeps waves inside one 32KB tile for
// L1 locality. Single merged accumulator (the 3 split-products share C) and
// -0.5||e||^2 folded into acc init. ~210 VGPR -> (512,2), no spill.
#define AP 260   // A-stage pitch (floats): 4-float pad -> 16B-aligned, 2-way-only banks

__global__ __launch_bounds__(512, 2)
void vq_mfma_k(const float* __restrict__ ze, float* __restrict__ ws) {
  __shared__ __align__(16) char ldsU[66560 + 4096];  // A-stage 64x260x4 + sCbn
  float* sCbn = (float*)(ldsU + 66560);

  const int t    = threadIdx.x;
  const int lane = t & 63;
  const int w    = t >> 6;          // 0..7
  const int ln31 = lane & 31;
  const int hl   = lane >> 5;
  const int mb   = blockIdx.x >> 2;
  const int cq   = blockIdx.x & 3;
  const int m0   = mb * 256;

  const float* cbn = ws;
  unsigned long long* pk = (unsigned long long*)((char*)ws + PK_OFF);
  const char* cbF = (const char*)ws + CBF_OFF;

  // ---- A into registers: 4 chunks of 64 rows staged fp32 through LDS ----
  s8v ah[16], al[16];
  float* Af = (float*)ldsU;
  for (int c = 0; c < 4; ++c) {
    __syncthreads();
    {
      int r  = t >> 3;          // 0..63
      int f0 = t & 7;
      const float* src = ze + (size_t)(m0 + c * 64 + r) * DIM;
      #pragma unroll
      for (int i = 0; i < 8; ++i) {
        int f = f0 + 8 * i;
        *(float4*)&Af[r * AP + f * 4] = *(const float4*)(src + f * 4);
      }
    }
    __syncthreads();
    if ((w >> 1) == c) {
      int rl = (w & 1) * 32 + ln31;
      #pragma unroll
      for (int ks = 0; ks < 16; ++ks) {
        float4 x0 = *(const float4*)&Af[rl * AP + ks * 16 + hl * 8];
        float4 x1 = *(const float4*)&Af[rl * AP + ks * 16 + hl * 8 + 4];
        float xs[8] = {x0.x, x0.y, x0.z, x0.w, x1.x, x1.y, x1.z, x1.w};
        #pragma unroll
        for (int j = 0; j < 8; ++j) {
          unsigned xb = __float_as_uint(xs[j]);
          unsigned hb = xb & 0xFFFF0000u;
          float lf = xs[j] - __uint_as_float(hb);
          ah[ks][j] = (short)(xb >> 16);
          al[ks][j] = (short)(__float_as_uint(lf) >> 16);
        }
      }
    }
  }
  // stage cbn for this block's 1024 cols (region disjoint from A-stage)
  sCbn[t]       = cbn[cq * 1024 + t];
  sCbn[t + 512] = cbn[cq * 1024 + 512 + t];
  __syncthreads();   // sCbn visible; A-stage LDS dead from here on

  // per-lane fragment base: tile tt, slice ks ->
  //   h at qb + tt*32768 + ks*1024 ; l at +16384
  const char* qb = cbF + (size_t)cq * 32 * 32768 + (size_t)lane * 16;

  float best[16];
  int   bidx[16];
  #pragma unroll
  for (int r = 0; r < 16; ++r) { best[r] = -1e30f; bidx[r] = 0; }

  // preload (tt=0, ks=0)
  s8v cbh = *(const s8v*)(qb);
  s8v cbl = *(const s8v*)(qb + 16384);

  #pragma unroll 1
  for (int tt = 0; tt < 32; ++tt) {
    __builtin_amdgcn_s_barrier();   // alignment only: keep 8 waves in one 32KB tile (L1)
    const char* tb = qb + (size_t)tt * 32768;
    const float half_cv = 0.5f * sCbn[tt * 32 + ln31];

    f16v acc;
    #pragma unroll
    for (int r = 0; r < 16; ++r) acc[r] = -half_cv;   // fold -0.5||e||^2 into C

    #pragma unroll
    for (int ks = 0; ks < 16; ++ks) {
      // 1-ahead prefetch: next (bh,bl) loads run under the 3 MFMAs
      s8v nbh, nbl;
      if (ks < 15) {
        nbh = *(const s8v*)(tb + (ks + 1) * 1024);
        nbl = *(const s8v*)(tb + 16384 + (ks + 1) * 1024);
      } else if (tt < 31) {
        nbh = *(const s8v*)(tb + 32768);
        nbl = *(const s8v*)(tb + 32768 + 16384);
      } else {
        nbh = cbh; nbl = cbl;
      }
      acc = __builtin_amdgcn_mfma_f32_32x32x16_bf16(ah[ks], cbh, acc, 0, 0, 0);
      acc = __builtin_amdgcn_mfma_f32_32x32x16_bf16(ah[ks], cbl, acc, 0, 0, 0);
      acc = __builtin_amdgcn_mfma_f32_32x32x16_bf16(al[ks], cbh, acc, 0, 0, 0);
      cbh = nbh; cbl = nbl;
    }

    // score = dot - 0.5||e||^2 (in acc); cols ascend with tt => '>' keeps first min
    const int c0 = cq * 1024 + tt * 32;
    #pragma unroll
    for (int r = 0; r < 16; ++r) {
      float s = acc[r];
      if (s > best[r]) { best[r] = s; bidx[r] = c0 + ln31; }
    }
  }

  // ---- cross-lane argmax over the 32 cols (masks<32 keep hl halves separate),
  // then device-scope packed atomicMax merge across the 4 col-split blocks ----
  #pragma unroll
  for (int r = 0; r < 16; ++r) {
    float s = best[r];
    int   c = bidx[r];
    #pragma unroll
    for (int mk = 1; mk < 32; mk <<= 1) {
      float os = __shfl_xor(s, mk, 64);
      int   oc = __shfl_xor(c, mk, 64);
      if (os > s || (os == s && oc < c)) { s = os; c = oc; }
    }
    if (ln31 == 0) {
      int row = m0 + w * 32 + (r & 3) + 8 * (r >> 2) + 4 * hl;
      unsigned u = __float_as_uint(s);
      unsigned enc = (u & 0x80000000u) ? ~u : (u | 0x80000000u);
      unsigned long long p = ((unsigned long long)enc << 32) | (unsigned)(KCB - 1 - c);
      atomicMax(&pk[row], p);
    }
  }
}

// ---- gather: indices out, counts, zq, loss partials ----
__global__ __launch_bounds__(256)
void gather_k(const float* __restrict__ ze, const float* __restrict__ cb,
              float* __restrict__ ws, float* __restrict__ out) {
  __shared__ int sIdx[64];
  const int t  = threadIdx.x;
  const int m0 = blockIdx.x * 64;
  float* counts   = ws + KCB;
  float* loss_sum = ws + 2 * KCB;
  const unsigned long long* pk = (const unsigned long long*)((const char*)ws + PK_OFF);

  if (t < 64) {
    unsigned long long p = pk[m0 + t];
    int col = KCB - 1 - (int)(unsigned)(p & 0xFFFFFFFFull);
    out[m0 + t] = (float)col;
    sIdx[t] = col;
    atomicAdd(&counts[col], 1.0f);
  }
  __syncthreads();

  float* out_zq = out + N_TOT;
  const int w = t >> 6, ln = t & 63;
  float lsum = 0.0f;
  #pragma unroll
  for (int p = 0; p < 16; ++p) {
    int r = w + 4 * p;
    float4 cvv = *(const float4*)(cb + (size_t)sIdx[r] * DIM + ln * 4);
    float4 zv  = *(const float4*)(ze + (size_t)(m0 + r) * DIM + ln * 4);
    *(float4*)(out_zq + (size_t)(m0 + r) * DIM + ln * 4) = cvv;
    float dx = cvv.x - zv.x, dy = cvv.y - zv.y, dz = cvv.z - zv.z, dw = cvv.w - zv.w;
    lsum += dx * dx + dy * dy + dz * dz + dw * dw;
  }
  #pragma unroll
  for (int off = 32; off > 0; off >>= 1) lsum += __shfl_down(lsum, off, 64);
  if (ln == 0) atomicAdd(loss_sum, lsum);
}

// ---------------- fallback (round-1 fp32 path, if ws too small) ----------------
__global__ void zero_ws_k(float* __restrict__ ws, int nw) {
  int i = blockIdx.x * 256 + threadIdx.x;
  if (i < nw) ws[KCB + i] = 0.0f;
}

__global__ void cbnorm_k(const float* __restrict__ cb, float* __restrict__ ws) {
  int row  = blockIdx.x * 4 + (threadIdx.x >> 6);
  int lane = threadIdx.x & 63;
  float4 v = *(const float4*)(cb + (size_t)row * DIM + lane * 4);
  float s = v.x*v.x + v.y*v.y + v.z*v.z + v.w*v.w;
  #pragma unroll
  for (int off = 32; off > 0; off >>= 1) s += __shfl_down(s, off, 64);
  if (lane == 0) ws[row] = s;
}

#define FBM 32
#define FBN 64
#define FBD 128
__global__ __launch_bounds__(256, 4)
void vq_main_k(const float* __restrict__ ze, const float* __restrict__ cb,
               float* __restrict__ ws, float* __restrict__ out) {
  __shared__ float As[FBM * FBD];
  __shared__ float Bs[FBN * FBD];
  __shared__ float red_d[FBM * 16];
  __shared__ int   red_i[FBM * 16];
  __shared__ int   sIdx[FBM];

  const int t  = threadIdx.x;
  const int tx = t & 15;
  const int ty = t >> 4;
  const int m0 = blockIdx.x * FBM;

  const float* cbn = ws;
  float* counts    = ws + KCB;
  float* loss_sum  = ws + 2 * KCB;

  float best0 = 1e30f, best1 = 1e30f;
  int   bidx0 = 0,     bidx1 = 0;
  const int sA = ty & 7;
  const int sB = tx & 7;

  for (int kt = 0; kt < KCB / FBN; ++kt) {
    float cbnj[4];
    #pragma unroll
    for (int j = 0; j < 4; ++j) cbnj[j] = cbn[kt * FBN + tx + 16 * j];
    float acc[2][4];
    #pragma unroll
    for (int i = 0; i < 2; ++i)
      #pragma unroll
      for (int j = 0; j < 4; ++j) acc[i][j] = 0.0f;

    for (int dc = 0; dc < DIM / FBD; ++dc) {
      __syncthreads();
      {
        int c  = t & 31;
        int rb = t >> 5;
        #pragma unroll
        for (int p = 0; p < 4; ++p) {
          int r = rb + 8 * p;
          float4 v = *(const float4*)(ze + (size_t)(m0 + r) * DIM + dc * FBD + c * 4);
          *(float4*)&As[r * FBD + ((c ^ (r & 7)) << 2)] = v;
        }
        #pragma unroll
        for (int p = 0; p < 8; ++p) {
          int r = rb + 8 * p;
          float4 v = *(const float4*)(cb + (size_t)(kt * FBN + r) * DIM + dc * FBD + c * 4);
          *(float4*)&Bs[r * FBD + ((c ^ (r & 7)) << 2)] = v;
        }
      }
      __syncthreads();
      #pragma unroll 8
      for (int ds = 0; ds < FBD / 4; ++ds) {
        float4 a0 = *(const float4*)&As[ty * FBD + ((ds ^ sA) << 2)];
        float4 a1 = *(const float4*)&As[(ty + 16) * FBD + ((ds ^ sA) << 2)];
        float4 b[4];
        #pragma unroll
        for (int j = 0; j < 4; ++j)
          b[j] = *(const float4*)&Bs[(tx + 16 * j) * FBD + ((ds ^ sB) << 2)];
        #pragma unroll
        for (int j = 0; j < 4; ++j) {
          acc[0][j] = fmaf(a0.x, b[j].x, acc[0][j]);
          acc[0][j] = fmaf(a0.y, b[j].y, acc[0][j]);
          acc[0][j] = fmaf(a0.z, b[j].z, acc[0][j]);
          acc[0][j] = fmaf(a0.w, b[j].w, acc[0][j]);
          acc[1][j] = fmaf(a1.x, b[j].x, acc[1][j]);
          acc[1][j] = fmaf(a1.y, b[j].y, acc[1][j]);
          acc[1][j] = fmaf(a1.z, b[j].z, acc[1][j]);
          acc[1][j] = fmaf(a1.w, b[j].w, acc[1][j]);
        }
      }
    }
    #pragma unroll
    for (int j = 0; j < 4; ++j) {
      int kg = kt * FBN + tx + 16 * j;
      float d0 = cbnj[j] - 2.0f * acc[0][j];
      float d1 = cbnj[j] - 2.0f * acc[1][j];
      if (d0 < best0) { best0 = d0; bidx0 = kg; }
      if (d1 < best1) { best1 = d1; bidx1 = kg; }
    }
  }

  __syncthreads();
  red_d[ty * 16 + tx] = best0;        red_i[ty * 16 + tx] = bidx0;
  red_d[(ty + 16) * 16 + tx] = best1; red_i[(ty + 16) * 16 + tx] = bidx1;
  __syncthreads();

  if (t < FBM) {
    float bd = red_d[t * 16]; int bi = red_i[t * 16];
    #pragma unroll
    for (int q = 1; q < 16; ++q) {
      float d = red_d[t * 16 + q]; int i2 = red_i[t * 16 + q];
      if (d < bd || (d == bd && i2 < bi)) { bd = d; bi = i2; }
    }
    out[m0 + t] = (float)bi;
    sIdx[t] = bi;
    atomicAdd(&counts[bi], 1.0f);
  }
  __syncthreads();

  float* out_zq = out + N_TOT;
  const int wv = t >> 6, ln = t & 63;
  float lsum = 0.0f;
  #pragma unroll
  for (int p = 0; p < 8; ++p) {
    int r = wv + 4 * p;
    float4 cvv = *(const float4*)(cb + (size_t)sIdx[r] * DIM + ln * 4);
    float4 zv  = *(const float4*)(ze + (size_t)(m0 + r) * DIM + ln * 4);
    *(float4*)(out_zq + (size_t)(m0 + r) * DIM + ln * 4) = cvv;
    float dx = cvv.x - zv.x, dy = cvv.y - zv.y, dz = cvv.z - zv.z, dw = cvv.w - zv.w;
    lsum += dx*dx + dy*dy + dz*dz + dw*dw;
  }
  #pragma unroll
  for (int off = 32; off > 0; off >>= 1) lsum += __shfl_down(lsum, off, 64);
  if (ln == 0) atomicAdd(loss_sum, lsum);
}

__global__ void finalize_k(const float* __restrict__ ws, float* __restrict__ out) {
  __shared__ float red[256];
  int t = threadIdx.x;
  const float* counts = ws + KCB;
  float s = 0.0f;
  for (int k = t; k < KCB; k += 256) {
    float p = counts[k] * 0.1f;
    s += p * logf(p + 1e-10f);
  }
  red[t] = s;
  __syncthreads();
  for (int q = 128; q > 0; q >>= 1) { if (t < q) red[t] += red[t + q]; __syncthreads(); }
  if (t == 0) {
    float loss = ws[2 * KCB] / (float)((size_t)N_TOT * DIM);
    float* o = out + N_TOT + (size_t)N_TOT * DIM;
    o[0] = loss;
    o[1] = loss;
    o[2] = expf(-red[0]);
  }
}

extern "C" void kernel_launch(void* const* d_in, const int* in_sizes, int n_in,
                              void* d_out, int out_size, void* d_ws, size_t ws_size,
                              hipStream_t stream) {
  const float* ze = (const float*)d_in[0];
  const float* cb = (const float*)d_in[1];
  float* out = (float*)d_out;
  float* ws  = (float*)d_ws;

  if (ws_size >= WS_NEED) {
    cb_prep_k<<<128, 256, 0, stream>>>(cb, ws);
    vq_mfma_k<<<256, 512, 0, stream>>>(ze, ws);
    gather_k<<<N_TOT / 64, 256, 0, stream>>>(ze, cb, ws, out);
  } else {
    zero_ws_k<<<(KCB + 1 + 255) / 256, 256, 0, stream>>>(ws, KCB + 1);
    cbnorm_k<<<KCB / 4, 256, 0, stream>>>(cb, ws);
    vq_main_k<<<N_TOT / FBM, 256, 0, stream>>>(ze, cb, ws, out);
  }
  finalize_k<<<1, 256, 0, stream>>>(ws, out);
}

// Round 7
// 193.398 us; speedup vs baseline: 1.2026x; 1.1134x over previous
//
#include <hip/hip_runtime.h>
#include <math.h>

// Problem constants (fixed by reference)
#define N_TOT 16384
#define DIM   256
#define KCB   4096

typedef __attribute__((ext_vector_type(8)))  short s8v;   // 8 bf16 = 4 VGPR
typedef __attribute__((ext_vector_type(16))) float f16v;  // MFMA 32x32 accumulator

// ---------------- ws layout (bytes) ----------------
// [0)      cbn    : 4096 f32 (||e_k||^2)
// [16384)  counts : 4096 f32
// [32768)  loss   : 1 f32 (+pad)
// [32832)  pk     : 16384 u64 (packed argmin merge)   -> 163904
// [163904) cbF    : fragment-linear split codebook, 128 tiles x 32KB = 4MB
//          tile t = cols [32t,32t+32): h 16KB then l 16KB.
//          h ushort idx within tile: ks*512 + khalf*256 + col*8 + j
//          (k = ks*16 + khalf*8 + j)  == LDS order  base + ks*1024 + lane*16
//          with lane = col + 32*khalf  -> global_load_lds is a linear memcpy.
#define PK_OFF   32832
#define CBF_OFF  163904
#define WS_NEED  4358208ull
#define ZERO_W   36880   // f32 words from ws[4096] covering counts+loss+pk

__device__ __forceinline__ void gload16(const void* g, void* l) {
  __builtin_amdgcn_global_load_lds(
      (const __attribute__((address_space(1))) unsigned int*)g,
      (__attribute__((address_space(3))) unsigned int*)l, 16, 0, 0);
}

// ---- codebook prep: zero ws counters, norms, fragment-linear h/l split ----
// 128 blocks (one per 32-col tile) x 256 threads. t -> (col = t>>3, j = t&7).
__global__ __launch_bounds__(256)
void cb_prep_k(const float* __restrict__ cb, float* __restrict__ ws) {
  const int t = threadIdx.x, tile = blockIdx.x;
  // fused zeroing of counts + loss + pk
  for (int i = tile * 256 + t; i < ZERO_W; i += 128 * 256) ws[KCB + i] = 0.0f;

  const int col = t >> 3, j = t & 7;
  const int c0  = tile * 32;
  ushort* tb = (ushort*)((char*)ws + CBF_OFF) + (size_t)tile * 16384;
  const float* src = cb + (size_t)(c0 + col) * DIM;
  float s = 0.0f;
  #pragma unroll
  for (int ks = 0; ks < 16; ++ks) {
    #pragma unroll
    for (int kh = 0; kh < 2; ++kh) {
      float x = src[ks * 16 + kh * 8 + j];
      s += x * x;
      unsigned xb = __float_as_uint(x);
      unsigned hb = xb & 0xFFFF0000u;
      float lf = x - __uint_as_float(hb);   // exact
      tb[ks * 512 + kh * 256 + t]        = (ushort)(xb >> 16);
      tb[8192 + ks * 512 + kh * 256 + t] = (ushort)(__float_as_uint(lf) >> 16);
    }
  }
  s += __shfl_down(s, 4, 8);
  s += __shfl_down(s, 2, 8);
  s += __shfl_down(s, 1, 8);
  if (j == 0) ws[c0 + col] = s;
}

// ---------------- main MFMA kernel ----------------
// 256 blocks x 512 threads (8 waves). Block = 256 rows x 1024 cols
// (mb = blockIdx>>2, cq = blockIdx&3). Round-0 structure (best measured:
// 102us, MfmaUtil 43%) with ONE change, testing the chain-latency theory:
// ROUND-7 THEORY: MfmaUtil tracks independent accumulator chains/wave
// (R6: 1 chain -> 33%; R0: 2 chains -> 43%). MFMA dependent-issue LATENCY
// (~150-240 clk, never isolated by the ubench which itself used multi-chain)
// makes R0's xx chain (2 serial MFMA/ks, depth 32/tile) the critical path:
// 32*L ~= the observed 7690-clk tile wall. Split xx into xa (ah*bl) and
// xb (al*bh): 3 independent chains, all depth 16. +16 VGPR (~240 total
// incl AGPRs, fits 2-wave/SIMD 256 budget - counted BEFORE benching this
// time). cbn staged to LDS (no global loads in loop); -0.5||e||^2 folded
// into hh init.
#define AP 260   // A-stage pitch (floats): 4-float pad -> 16B-aligned, 2-way-only banks

__global__ __launch_bounds__(512, 2)
void vq_mfma_k(const float* __restrict__ ze, float* __restrict__ ws) {
  __shared__ __align__(16) char ldsU[66560 + 4096];   // max(A 64x260x4, B 2x32KB) + sCbn
  float* sCbn = (float*)(ldsU + 66560);

  const int t    = threadIdx.x;
  const int lane = t & 63;
  const int w    = t >> 6;
  const int ln31 = lane & 31;
  const int hl   = lane >> 5;
  const int mb   = blockIdx.x >> 2;
  const int cq   = blockIdx.x & 3;
  const int m0   = mb * 256;

  const float* cbn = ws;
  unsigned long long* pk = (unsigned long long*)((char*)ws + PK_OFF);
  const char* cbF = (const char*)ws + CBF_OFF;

  // ---- A into registers: 4 chunks of 64 rows staged fp32 through LDS ----
  s8v ah[16], al[16];
  float* Af = (float*)ldsU;
  for (int c = 0; c < 4; ++c) {
    __syncthreads();
    {
      int r  = t >> 3;          // 0..63
      int f0 = t & 7;
      const float* src = ze + (size_t)(m0 + c * 64 + r) * DIM;
      #pragma unroll
      for (int i = 0; i < 8; ++i) {
        int f = f0 + 8 * i;
        *(float4*)&Af[r * AP + f * 4] = *(const float4*)(src + f * 4);
      }
    }
    __syncthreads();
    if ((w >> 1) == c) {
      int rl = (w & 1) * 32 + ln31;
      #pragma unroll
      for (int ks = 0; ks < 16; ++ks) {
        float4 x0 = *(const float4*)&Af[rl * AP + ks * 16 + hl * 8];
        float4 x1 = *(const float4*)&Af[rl * AP + ks * 16 + hl * 8 + 4];
        float xs[8] = {x0.x, x0.y, x0.z, x0.w, x1.x, x1.y, x1.z, x1.w};
        #pragma unroll
        for (int j = 0; j < 8; ++j) {
          unsigned xb = __float_as_uint(xs[j]);
          unsigned hb = xb & 0xFFFF0000u;
          float lf = xs[j] - __uint_as_float(hb);
          ah[ks][j] = (short)(xb >> 16);
          al[ks][j] = (short)(__float_as_uint(lf) >> 16);
        }
      }
    }
  }
  // stage cbn for this block's 1024 cols (region disjoint from A-stage)
  sCbn[t]       = cbn[cq * 1024 + t];
  sCbn[t + 512] = cbn[cq * 1024 + 512 + t];
  __syncthreads();   // A-region reads + sCbn writes done before B staging overwrites ldsU

  char* bufs0 = ldsU;
  char* bufs1 = ldsU + 32768;
  const char* qbase = cbF + (size_t)cq * 32 * 32768;

  // issue tile 0 (4 x 1KB per wave = 32KB total)
  {
    const char* g = qbase + (size_t)w * 4096 + (size_t)lane * 16;
    char* lp = bufs0 + w * 4096;
    #pragma unroll
    for (int ii = 0; ii < 4; ++ii) gload16(g + ii * 1024, lp + ii * 1024);
  }

  float best[16];
  int   bidx[16];
  #pragma unroll
  for (int r = 0; r < 16; ++r) { best[r] = -1e30f; bidx[r] = 0; }

  #pragma unroll 1
  for (int tt = 0; tt < 32; ++tt) {
    __syncthreads();   // drains vmcnt: buf[tt&1] ready; all reads of buf[(tt+1)&1] done
    if (tt + 1 < 32) {
      const char* g = qbase + (size_t)(tt + 1) * 32768 + (size_t)w * 4096 + (size_t)lane * 16;
      char* lp = ((tt + 1) & 1 ? bufs1 : bufs0) + w * 4096;
      #pragma unroll
      for (int ii = 0; ii < 4; ++ii) gload16(g + ii * 1024, lp + ii * 1024);
    }

    const int   c0      = cq * 1024 + tt * 32;
    const float half_cv = 0.5f * sCbn[tt * 32 + ln31];
    const char* bc      = (tt & 1) ? bufs1 : bufs0;

    // 3 INDEPENDENT accumulator chains (depth 16 each): hh, xa, xb
    f16v hh, xa, xb;
    #pragma unroll
    for (int r = 0; r < 16; ++r) { hh[r] = -half_cv; xa[r] = 0.0f; xb[r] = 0.0f; }

    #pragma unroll
    for (int ks = 0; ks < 16; ++ks) {
      s8v bh = *(const s8v*)(bc + ks * 1024 + lane * 16);
      s8v bl = *(const s8v*)(bc + 16384 + ks * 1024 + lane * 16);
      hh = __builtin_amdgcn_mfma_f32_32x32x16_bf16(ah[ks], bh, hh, 0, 0, 0);
      xa = __builtin_amdgcn_mfma_f32_32x32x16_bf16(ah[ks], bl, xa, 0, 0, 0);
      xb = __builtin_amdgcn_mfma_f32_32x32x16_bf16(al[ks], bh, xb, 0, 0, 0);
    }

    // score = dot - 0.5||e||^2 (folded into hh init);
    // cols ascend with tt => '>' keeps first min
    #pragma unroll
    for (int r = 0; r < 16; ++r) {
      float s = hh[r] + xa[r] + xb[r];
      if (s > best[r]) { best[r] = s; bidx[r] = c0 + ln31; }
    }
  }

  // ---- cross-lane argmax over the 32 cols (masks<32 keep hl halves separate),
  // then device-scope packed atomicMax merge across the 4 col-split blocks ----
  #pragma unroll
  for (int r = 0; r < 16; ++r) {
    float s = best[r];
    int   c = bidx[r];
    #pragma unroll
    for (int mk = 1; mk < 32; mk <<= 1) {
      float os = __shfl_xor(s, mk, 64);
      int   oc = __shfl_xor(c, mk, 64);
      if (os > s || (os == s && oc < c)) { s = os; c = oc; }
    }
    if (ln31 == 0) {
      int row = m0 + w * 32 + (r & 3) + 8 * (r >> 2) + 4 * hl;
      unsigned u = __float_as_uint(s);
      unsigned enc = (u & 0x80000000u) ? ~u : (u | 0x80000000u);
      unsigned long long p = ((unsigned long long)enc << 32) | (unsigned)(KCB - 1 - c);
      atomicMax(&pk[row], p);
    }
  }
}

// ---- gather: indices out, counts, zq, loss partials ----
__global__ __launch_bounds__(256)
void gather_k(const float* __restrict__ ze, const float* __restrict__ cb,
              float* __restrict__ ws, float* __restrict__ out) {
  __shared__ int sIdx[64];
  const int t  = threadIdx.x;
  const int m0 = blockIdx.x * 64;
  float* counts   = ws + KCB;
  float* loss_sum = ws + 2 * KCB;
  const unsigned long long* pk = (const unsigned long long*)((const char*)ws + PK_OFF);

  if (t < 64) {
    unsigned long long p = pk[m0 + t];
    int col = KCB - 1 - (int)(unsigned)(p & 0xFFFFFFFFull);
    out[m0 + t] = (float)col;
    sIdx[t] = col;
    atomicAdd(&counts[col], 1.0f);
  }
  __syncthreads();

  float* out_zq = out + N_TOT;
  const int w = t >> 6, ln = t & 63;
  float lsum = 0.0f;
  #pragma unroll
  for (int p = 0; p < 16; ++p) {
    int r = w + 4 * p;
    float4 cvv = *(const float4*)(cb + (size_t)sIdx[r] * DIM + ln * 4);
    float4 zv  = *(const float4*)(ze + (size_t)(m0 + r) * DIM + ln * 4);
    *(float4*)(out_zq + (size_t)(m0 + r) * DIM + ln * 4) = cvv;
    float dx = cvv.x - zv.x, dy = cvv.y - zv.y, dz = cvv.z - zv.z, dw = cvv.w - zv.w;
    lsum += dx * dx + dy * dy + dz * dz + dw * dw;
  }
  #pragma unroll
  for (int off = 32; off > 0; off >>= 1) lsum += __shfl_down(lsum, off, 64);
  if (ln == 0) atomicAdd(loss_sum, lsum);
}

// ---------------- fallback (round-1 fp32 path, if ws too small) ----------------
__global__ void zero_ws_k(float* __restrict__ ws, int nw) {
  int i = blockIdx.x * 256 + threadIdx.x;
  if (i < nw) ws[KCB + i] = 0.0f;
}

__global__ void cbnorm_k(const float* __restrict__ cb, float* __restrict__ ws) {
  int row  = blockIdx.x * 4 + (threadIdx.x >> 6);
  int lane = threadIdx.x & 63;
  float4 v = *(const float4*)(cb + (size_t)row * DIM + lane * 4);
  float s = v.x*v.x + v.y*v.y + v.z*v.z + v.w*v.w;
  #pragma unroll
  for (int off = 32; off > 0; off >>= 1) s += __shfl_down(s, off, 64);
  if (lane == 0) ws[row] = s;
}

#define FBM 32
#define FBN 64
#define FBD 128
__global__ __launch_bounds__(256, 4)
void vq_main_k(const float* __restrict__ ze, const float* __restrict__ cb,
               float* __restrict__ ws, float* __restrict__ out) {
  __shared__ float As[FBM * FBD];
  __shared__ float Bs[FBN * FBD];
  __shared__ float red_d[FBM * 16];
  __shared__ int   red_i[FBM * 16];
  __shared__ int   sIdx[FBM];

  const int t  = threadIdx.x;
  const int tx = t & 15;
  const int ty = t >> 4;
  const int m0 = blockIdx.x * FBM;

  const float* cbn = ws;
  float* counts    = ws + KCB;
  float* loss_sum  = ws + 2 * KCB;

  float best0 = 1e30f, best1 = 1e30f;
  int   bidx0 = 0,     bidx1 = 0;
  const int sA = ty & 7;
  const int sB = tx & 7;

  for (int kt = 0; kt < KCB / FBN; ++kt) {
    float cbnj[4];
    #pragma unroll
    for (int j = 0; j < 4; ++j) cbnj[j] = cbn[kt * FBN + tx + 16 * j];
    float acc[2][4];
    #pragma unroll
    for (int i = 0; i < 2; ++i)
      #pragma unroll
      for (int j = 0; j < 4; ++j) acc[i][j] = 0.0f;

    for (int dc = 0; dc < DIM / FBD; ++dc) {
      __syncthreads();
      {
        int c  = t & 31;
        int rb = t >> 5;
        #pragma unroll
        for (int p = 0; p < 4; ++p) {
          int r = rb + 8 * p;
          float4 v = *(const float4*)(ze + (size_t)(m0 + r) * DIM + dc * FBD + c * 4);
          *(float4*)&As[r * FBD + ((c ^ (r & 7)) << 2)] = v;
        }
        #pragma unroll
        for (int p = 0; p < 8; ++p) {
          int r = rb + 8 * p;
          float4 v = *(const float4*)(cb + (size_t)(kt * FBN + r) * DIM + dc * FBD + c * 4);
          *(float4*)&Bs[r * FBD + ((c ^ (r & 7)) << 2)] = v;
        }
      }
      __syncthreads();
      #pragma unroll 8
      for (int ds = 0; ds < FBD / 4; ++ds) {
        float4 a0 = *(const float4*)&As[ty * FBD + ((ds ^ sA) << 2)];
        float4 a1 = *(const float4*)&As[(ty + 16) * FBD + ((ds ^ sA) << 2)];
        float4 b[4];
        #pragma unroll
        for (int j = 0; j < 4; ++j)
          b[j] = *(const float4*)&Bs[(tx + 16 * j) * FBD + ((ds ^ sB) << 2)];
        #pragma unroll
        for (int j = 0; j < 4; ++j) {
          acc[0][j] = fmaf(a0.x, b[j].x, acc[0][j]);
          acc[0][j] = fmaf(a0.y, b[j].y, acc[0][j]);
          acc[0][j] = fmaf(a0.z, b[j].z, acc[0][j]);
          acc[0][j] = fmaf(a0.w, b[j].w, acc[0][j]);
          acc[1][j] = fmaf(a1.x, b[j].x, acc[1][j]);
          acc[1][j] = fmaf(a1.y, b[j].y, acc[1][j]);
          acc[1][j] = fmaf(a1.z, b[j].z, acc[1][j]);
          acc[1][j] = fmaf(a1.w, b[j].w, acc[1][j]);
        }
      }
    }
    #pragma unroll
    for (int j = 0; j < 4; ++j) {
      int kg = kt * FBN + tx + 16 * j;
      float d0 = cbnj[j] - 2.0f * acc[0][j];
      float d1 = cbnj[j] - 2.0f * acc[1][j];
      if (d0 < best0) { best0 = d0; bidx0 = kg; }
      if (d1 < best1) { best1 = d1; bidx1 = kg; }
    }
  }

  __syncthreads();
  red_d[ty * 16 + tx] = best0;        red_i[ty * 16 + tx] = bidx0;
  red_d[(ty + 16) * 16 + tx] = best1; red_i[(ty + 16) * 16 + tx] = bidx1;
  __syncthreads();

  if (t < FBM) {
    float bd = red_d[t * 16]; int bi = red_i[t * 16];
    #pragma unroll
    for (int q = 1; q < 16; ++q) {
      float d = red_d[t * 16 + q]; int i2 = red_i[t * 16 + q];
      if (d < bd || (d == bd && i2 < bi)) { bd = d; bi = i2; }
    }
    out[m0 + t] = (float)bi;
    sIdx[t] = bi;
    atomicAdd(&counts[bi], 1.0f);
  }
  __syncthreads();

  float* out_zq = out + N_TOT;
  const int wv = t >> 6, ln = t & 63;
  float lsum = 0.0f;
  #pragma unroll
  for (int p = 0; p < 8; ++p) {
    int r = wv + 4 * p;
    float4 cvv = *(const float4*)(cb + (size_t)sIdx[r] * DIM + ln * 4);
    float4 zv  = *(const float4*)(ze + (size_t)(m0 + r) * DIM + ln * 4);
    *(float4*)(out_zq + (size_t)(m0 + r) * DIM + ln * 4) = cvv;
    float dx = cvv.x - zv.x, dy = cvv.y - zv.y, dz = cvv.z - zv.z, dw = cvv.w - zv.w;
    lsum += dx*dx + dy*dy + dz*dz + dw*dw;
  }
  #pragma unroll
  for (int off = 32; off > 0; off >>= 1) lsum += __shfl_down(lsum, off, 64);
  if (ln == 0) atomicAdd(loss_sum, lsum);
}

__global__ void finalize_k(const float* __restrict__ ws, float* __restrict__ out) {
  __shared__ float red[256];
  int t = threadIdx.x;
  const float* counts = ws + KCB;
  float s = 0.0f;
  for (int k = t; k < KCB; k += 256) {
    float p = counts[k] * 0.1f;
    s += p * logf(p + 1e-10f);
  }
  red[t] = s;
  __syncthreads();
  for (int q = 128; q > 0; q >>= 1) { if (t < q) red[t] += red[t + q]; __syncthreads(); }
  if (t == 0) {
    float loss = ws[2 * KCB] / (float)((size_t)N_TOT * DIM);
    float* o = out + N_TOT + (size_t)N_TOT * DIM;
    o[0] = loss;
    o[1] = loss;
    o[2] = expf(-red[0]);
  }
}

extern "C" void kernel_launch(void* const* d_in, const int* in_sizes, int n_in,
                              void* d_out, int out_size, void* d_ws, size_t ws_size,
                              hipStream_t stream) {
  const float* ze = (const float*)d_in[0];
  const float* cb = (const float*)d_in[1];
  float* out = (float*)d_out;
  float* ws  = (float*)d_ws;

  if (ws_size >= WS_NEED) {
    cb_prep_k<<<128, 256, 0, stream>>>(cb, ws);
    vq_mfma_k<<<256, 512, 0, stream>>>(ze, ws);
    gather_k<<<N_TOT / 64, 256, 0, stream>>>(ze, cb, ws, out);
  } else {
    zero_ws_k<<<(KCB + 1 + 255) / 256, 256, 0, stream>>>(ws, KCB + 1);
    cbnorm_k<<<KCB / 4, 256, 0, stream>>>(cb, ws);
    vq_main_k<<<N_TOT / FBM, 256, 0, stream>>>(ze, cb, ws, out);
  }
  finalize_k<<<1, 256, 0, stream>>>(ws, out);
}